// Round 13
// baseline (433.460 us; speedup 1.0000x reference)
//
#include <hip/hip_runtime.h>

// FirUpsample R12: BARRIER-FREE main loop. R3-R11 all ran 103-135us with all
// pipes idle -- the invariant was the schedule: stage -> barrier -> ~6 MFMA ->
// barrier at tiny granularity (the measured ~72%-stall structure). R12 makes
// A (= w bf16) AND B (= x bf16) LDS-resident per ic-half pass, so the K-loop
// is pure ds_read+MFMA with no barriers/staging inside.
//   math (verified R5-R11, absmax 0.015625): h = dilated conv3x3 as 4 parity-
//   plane GEMMs (K 4/2/2/1 taps x 256 ic); separable 4-tap FIR epilogue.
// Block: 32 oc x (4 coarse rows x 16 coarse cols out-tile), 512 thr, 4 btile
// reps x 2 ic-half passes. LDS: As[9][32][128] pad-272 (78336 B) +
// xs[108][128] pad-272 (29376 B); hl[4][8][6][20] aliases xs in epilogue.
// 272-B row pads make all A/B b128 reads bank-conflict-free ((row+slot)&7).

typedef short bf16x8 __attribute__((ext_vector_type(8)));
typedef short short4v __attribute__((ext_vector_type(4)));
typedef float f32x16 __attribute__((ext_vector_type(16)));
typedef float f32x4v __attribute__((ext_vector_type(4)));

static __device__ __forceinline__ short f2bf(float f) {
  union { float f; unsigned u; } v; v.f = f;
  unsigned r = (v.u + 0x7FFFu + ((v.u >> 16) & 1u)) >> 16;
  return (short)r;
}
static __device__ __forceinline__ float bf2f(short s) {
  union { unsigned u; float f; } v; v.u = ((unsigned)(unsigned short)s) << 16;
  return v.f;
}

#define AS_KQ 8704      // 32*272
#define AS_OC 272
#define AS_BYTES 78336  // 9*8704
#define XS_CELL 272
#define LDS_BYTES (78336 + 29376)

__global__ __launch_bounds__(512, 1)
void fir_up_v12(const float* __restrict__ x, const float* __restrict__ w,
                float* __restrict__ out) {
  __shared__ __align__(16) char smem[LDS_BYTES];
  char* Ab = smem;
  char* xb = smem + AS_BYTES;

  const int bid = blockIdx.x;
  const int octile = bid & 7;          // xcd-pinned w-slice (295 KB, L2-resident)
  const int atile = (bid >> 3) & 15;   // 16 tiles of 4 coarse rows
  const int n = bid >> 7;              // 0..3
  const int A0c = atile * 4;

  const int tid = threadIdx.x;
  const int wid = tid >> 6;
  const int lane = tid & 63;
  const int l31 = lane & 31, q = lane >> 5;

  // ---- plane geometry (R5-verified tables; rows for 4-coarse tiles) ----
  const int COLSt[4]  = {17, 18, 17, 18};
  const int CELLSt[4] = {85, 90, 102, 108};   // 5x17, 5x18, 6x17, 6x18
  const int NKt[4]    = {4, 2, 2, 1};
  const int KQt[4][4] = {{0,2,6,8},{1,7,7,7},{3,5,5,5},{4,4,4,4}};
  const int DYt[4][4] = {{0,0,1,1},{0,1,1,1},{0,0,0,0},{0,0,0,0}};
  const int DXt[4][4] = {{0,1,0,1},{0,0,0,0},{0,1,1,1},{0,0,0,0}};

  // ---- per-wave segment partition: up to 2 segs of (plane, fgbase, nfg) ----
  // ks/cc: w0..w7 = 4,4,4,4,3,4,4,3 (balanced); SIMD pairs balanced too.
  const int SGP[8][2] = {{0,0},{0,0},{0,0},{1,1},{1,3},{2,2},{2,2},{3,3}};
  const int SGF[8][2] = {{0,0},{1,0},{2,0},{0,0},{2,3},{0,0},{2,0},{0,0}};
  const int SGN[8][2] = {{1,0},{1,0},{1,0},{2,0},{1,1},{2,0},{2,0},{3,0}};

  int aof[2][4], bb[2][3][4], hb[2][3], segnk[2], segnf[2];
  bool vld[2][3];
#pragma unroll
  for (int sg = 0; sg < 2; ++sg) {
    const int p = SGP[wid][sg];
    segnk[sg] = NKt[p];
    segnf[sg] = SGN[wid][sg];
#pragma unroll
    for (int s = 0; s < 4; ++s) aof[sg][s] = KQt[p][s] * AS_KQ + l31 * AS_OC;
#pragma unroll
    for (int fg = 0; fg < 3; ++fg) {
      const int cellraw = (SGF[wid][sg] + fg) * 32 + l31;
      const bool valid = (fg < segnf[sg]) && (cellraw < CELLSt[p]);
      const int cell = valid ? cellraw : 0;
      const int cols = COLSt[p];
      const int r = cell / cols;
      const int c = cell - r * cols;
      vld[sg][fg] = valid;
      hb[sg][fg] = p * 960 + r * 20 + c;   // hl: plane 960, ocl 120, row 20 (shorts)
#pragma unroll
      for (int s = 0; s < 4; ++s)
        bb[sg][fg][s] = ((r + DYt[p][s]) * 18 + (c + DXt[p][s])) * XS_CELL;
    }
  }

  const float kf4[4] = {0.25f, 0.75f, 0.75f, 0.25f};

  // ---- btile reps ----
  for (int btile = 0; btile < 4; ++btile) {
    const int B0 = btile * 16;

    f32x16 acc[2][3];
#pragma unroll
    for (int sg = 0; sg < 2; ++sg)
#pragma unroll
      for (int fg = 0; fg < 3; ++fg)
#pragma unroll
        for (int e = 0; e < 16; ++e) acc[sg][fg][e] = 0.f;

    // ---- 2 ic-half passes: stage everything, then barrier-free MFMA ----
    for (int pass = 0; pass < 2; ++pass) {
      __syncthreads();   // previous pass reads / epilogue / prev rep done

      // stage As half: 9216 f4s of w (coalesced), scatter b16 into padded rows
#pragma unroll
      for (int it = 0; it < 18; ++it) {
        const int f = tid + it * 512;
        const int oc = f / 288;
        const int rem = f - oc * 288;
        const f32x4v v = *(const f32x4v*)(
            w + (size_t)(octile * 32 + oc) * 2304 + pass * 1152 + rem * 4);
#pragma unroll
        for (int e = 0; e < 4; ++e) {
          const int flat = pass * 1152 + rem * 4 + e;
          const int ic = flat / 9;
          const int kq = flat - ic * 9;
          const int icl = ic - pass * 128;
          *(short*)(Ab + kq * AS_KQ + oc * AS_OC + icl * 2) = f2bf(v[e]);
        }
      }
      // stage xs half: 4608 units (ic128 x row6 x f4g6), f4 row loads
#pragma unroll
      for (int it = 0; it < 9; ++it) {
        const int u = tid + it * 512;
        const int ic = u / 36;
        const int rem = u - ic * 36;
        const int row = rem / 6;
        const int f4g = rem - row * 6;
        const int gh = A0c - 1 + row;
        const bool rowok = (gh >= 0) & (gh < 64);
        const int gw0 = B0 - 4 + 4 * f4g;
        float v[4];
        const float* base =
            x + (((size_t)(n * 256 + pass * 128 + ic)) * 64 + (rowok ? gh : 0)) * 64;
        if (rowok & (gw0 >= 0) & (gw0 <= 60)) {
          const f32x4v fv = *(const f32x4v*)(base + gw0);
#pragma unroll
          for (int e = 0; e < 4; ++e) v[e] = fv[e];
        } else {
#pragma unroll
          for (int e = 0; e < 4; ++e) {
            const int gw = gw0 + e;
            v[e] = (rowok && gw >= 0 && gw < 64) ? base[gw] : 0.f;
          }
        }
#pragma unroll
        for (int e = 0; e < 4; ++e) {
          const int ww = 4 * f4g + e - 3;
          if (ww >= 0 && ww < 18)
            *(short*)(xb + (row * 18 + ww) * XS_CELL + ic * 2) = f2bf(v[e]);
        }
      }
      __syncthreads();   // operands resident

      // ---- barrier-free MFMA: 8 chunks x segments ----
      for (int cc = 0; cc < 8; ++cc) {
        const int slotb = (cc * 2 + q) * 16;
#pragma unroll
        for (int sg = 0; sg < 2; ++sg) {
#pragma unroll
          for (int s = 0; s < 4; ++s) {
            if (s < segnk[sg] && segnf[sg] > 0) {
              const bf16x8 A = *(const bf16x8*)(Ab + aof[sg][s] + slotb);
#pragma unroll
              for (int fg = 0; fg < 3; ++fg) {
                if (fg < segnf[sg]) {
                  const bf16x8 B = *(const bf16x8*)(xb + bb[sg][fg][s] + slotb);
                  acc[sg][fg] =
                      __builtin_amdgcn_mfma_f32_32x32x16_bf16(A, B, acc[sg][fg], 0, 0, 0);
                }
              }
            }
          }
        }
      }
    }

    // ---- epilogue: 4 sub-phases of 8 ocs; hl aliases xs region ----
    short* hl = (short*)xb;
#pragma unroll
    for (int g8 = 0; g8 < 4; ++g8) {
      __syncthreads();   // MFMA reads done (phase 0) / prev FIR done
#pragma unroll
      for (int sg = 0; sg < 2; ++sg)
#pragma unroll
        for (int fg = 0; fg < 3; ++fg) {
          if (vld[sg][fg]) {
#pragma unroll
            for (int jj = 0; jj < 4; ++jj)
              hl[hb[sg][fg] + (jj + 4 * q) * 120] = f2bf(acc[sg][fg][4 * g8 + jj]);
          }
        }
      __syncthreads();

      if (tid < 256) {
        const int g = tid & 3;
        const int Yl = (tid >> 2) & 7;
        const int o8 = tid >> 5;
        float o[8];
#pragma unroll
        for (int xx = 0; xx < 8; ++xx) o[xx] = 0.f;
#pragma unroll
        for (int du = 0; du < 4; ++du) {
          const int ttp = Yl - 1 + du;
          const int py = ttp & 1;
          const int r = py ? ((Yl + du) >> 1) : (ttp >> 1);
          const int baseE = (py * 2) * 960 + o8 * 120 + r * 20 + 4 * g;
          const int baseO = baseE + 960;
          const short4v e0 = *(const short4v*)(hl + baseE);
          const short4v e1 = *(const short4v*)(hl + baseE + 4);
          const short4v o0 = *(const short4v*)(hl + baseO);
          const short4v o1 = *(const short4v*)(hl + baseO + 4);
          float E[8], O[8];
#pragma unroll
          for (int i = 0; i < 4; ++i) {
            E[i] = bf2f(e0[i]); E[i + 4] = bf2f(e1[i]);
            O[i] = bf2f(o0[i]); O[i + 4] = bf2f(o1[i]);
          }
          float rx[8];
          rx[0] = 0.25f*O[0] + 0.75f*E[0] + 0.75f*O[1] + 0.25f*E[1];
          rx[1] = 0.25f*E[0] + 0.75f*O[1] + 0.75f*E[1] + 0.25f*O[2];
          rx[2] = 0.25f*O[1] + 0.75f*E[1] + 0.75f*O[2] + 0.25f*E[2];
          rx[3] = 0.25f*E[1] + 0.75f*O[2] + 0.75f*E[2] + 0.25f*O[3];
          rx[4] = 0.25f*O[2] + 0.75f*E[2] + 0.75f*O[3] + 0.25f*E[3];
          rx[5] = 0.25f*E[2] + 0.75f*O[3] + 0.75f*E[3] + 0.25f*O[4];
          rx[6] = 0.25f*O[3] + 0.75f*E[3] + 0.75f*O[4] + 0.25f*E[4];
          rx[7] = 0.25f*E[3] + 0.75f*O[4] + 0.75f*E[4] + 0.25f*O[5];
          const float ky = kf4[du];
#pragma unroll
          for (int xx = 0; xx < 8; ++xx) o[xx] += ky * rx[xx];
        }
        const int oc = octile * 32 + g8 * 8 + o8;
        const int Y = atile * 8 + Yl;
        const int X0 = btile * 32 + g * 8;
        float* op = out + (((size_t)(n * 256 + oc)) * 128 + Y) * 128 + X0;
        f32x4v w0, w1;
        w0[0] = o[0]; w0[1] = o[1]; w0[2] = o[2]; w0[3] = o[3];
        w1[0] = o[4]; w1[1] = o[5]; w1[2] = o[6]; w1[3] = o[7];
        *(f32x4v*)op = w0;
        *(f32x4v*)(op + 4) = w1;
      }
    }
  }
}

extern "C" void kernel_launch(void* const* d_in, const int* in_sizes, int n_in,
                              void* d_out, int out_size, void* d_ws, size_t ws_size,
                              hipStream_t stream) {
  (void)in_sizes; (void)n_in; (void)out_size; (void)d_ws; (void)ws_size;
  const float* x = (const float*)d_in[0];
  const float* w = (const float*)d_in[1];
  float* out = (float*)d_out;
  // grid = 8 octiles x 16 atiles x 4 n = 512 blocks, 512 threads
  hipLaunchKernelGGL(fir_up_v12, dim3(512), dim3(512), 0, stream, x, w, out);
}

// Round 14
// 102.711 us; speedup vs baseline: 4.2202x; 4.2202x over previous
//
#include <hip/hip_runtime.h>

// FirUpsample R13 = R7 VERBATIM except the x-stage gather is actually
// coalesced this time. R11 claimed to coalesce but put ic in the lane-minor
// position (u = f4g*160+gh*16+ic) -> 16 consecutive lanes read 16 different
// ics at 16KB stride = one line per lane, same as R5-R8. R13 uses
// u = ic*60 + row*6 + f4g (f4g minor): lanes sweep aligned float4s along a
// row -> ~22 lines/wave-instr vs 64. Everything else is R7 (103.5us, passed):
//   Stage 1 (MFMA): h = dilated conv3x3(x,w) as 4 parity-plane GEMMs
//     (K-depth 4/2/2/1 x 256 ic = 10.3 G MAC).
//   Stage 2 (VALU): separable 4-tap FIR on h (bf16 in LDS), fp32 out.

typedef short bf16x4 __attribute__((ext_vector_type(4)));
typedef short bf16x8 __attribute__((ext_vector_type(8)));
typedef short short4v __attribute__((ext_vector_type(4)));
typedef float f32x16 __attribute__((ext_vector_type(16)));
typedef float f32x4v __attribute__((ext_vector_type(4)));

static __device__ __forceinline__ short f2bf(float f) {
  union { float f; unsigned u; } v; v.f = f;
  unsigned r = (v.u + 0x7FFFu + ((v.u >> 16) & 1u)) >> 16;
  return (short)r;
}
static __device__ __forceinline__ float bf2f(short s) {
  union { unsigned u; float f; } v; v.u = ((unsigned)(unsigned short)s) << 16;
  return v.f;
}

__global__ __launch_bounds__(512)
void fir_up_v13(const float* __restrict__ x, const float* __restrict__ w,
                float* __restrict__ out) {
  // XCD swizzle: xcd = bid&7; octile-major so each XCD pair shares a w-slice.
  const int bid = blockIdx.x;
  const int wg = (bid & 7) * 64 + (bid >> 3);
  const int octile = wg >> 7;        // 0..3 (64 oc each)
  const int n = (wg >> 5) & 3;
  const int sp = wg & 31;
  const int atile = sp >> 2;         // 0..7 coarse-row tiles (8 rows each)
  const int btile = sp & 3;          // 0..3 coarse-col tiles (16 cols each)
  const int A0 = atile * 8, B0 = btile * 16;

  const int tid = threadIdx.x;
  const int wid = tid >> 6;
  const int lane = tid & 63;
  const int l31 = lane & 31, q = lane >> 5;

  __shared__ short As[9 * 64 * 16];       // [kq][oc64][ic16]  18.4 KB
  __shared__ short xs[180 * 16];          // [cell=r*18+c][ic16] 5.76 KB
  __shared__ short hl[4 * 32 * 10 * 20];  // [plane][ocl][r][c(pad 20)] 51.2 KB

  // plane geometry: p = py*2+px ; rows: even 9 odd 10 ; cols: even 17 odd 18
  const int COLSt[4]  = {17, 18, 17, 18};
  const int CELLSt[4] = {153, 162, 170, 180};
  const int NKt[4]    = {4, 2, 2, 1};
  const int KQt[4][4] = {{0,2,6,8},{1,7,7,7},{3,5,5,5},{4,4,4,4}};
  const int DYt[4][4] = {{0,0,1,1},{0,1,1,1},{0,0,0,0},{0,0,0,0}};
  const int DXt[4][4] = {{0,1,0,1},{0,0,0,0},{0,1,1,1},{0,0,0,0}};

  // per-wave frag assignment (8 waves x 3 slots), K-balanced (R5-verified)
  const unsigned long long PLbits =
      (0x34ULL) | (0x34ULL << 6) | (0x34ULL << 12) | (0x38ULL << 18) |
      (0x38ULL << 24) | (0x38ULL << 30) | (0x15ULL << 36) | (0x2AULL << 42);
  const unsigned FG0 = 0u | 1u<<3 | 2u<<6 | 3u<<9 | 4u<<12 | 5u<<15 | 3u<<18 | 3u<<21;
  const unsigned FG1 = 0u | 1u<<3 | 2u<<6 | 0u<<9 | 1u<<12 | 2u<<15 | 4u<<18 | 4u<<21;
  const unsigned FG2 = 0u | 1u<<3 | 2u<<6 | 3u<<9 | 4u<<12 | 5u<<15 | 5u<<18 | 5u<<21;

  int nkS[3], validS[3], hbaseS[3];
  int kqS[3][4], cellxS[3][4];
#pragma unroll
  for (int slot = 0; slot < 3; ++slot) {
    const int p = (int)((PLbits >> ((wid * 3 + slot) * 2)) & 3ULL);
    const unsigned fgw = slot == 0 ? FG0 : (slot == 1 ? FG1 : FG2);
    const int fg = (int)((fgw >> (3 * wid)) & 7u);
    const int cellraw = fg * 32 + l31;
    const int valid = cellraw < CELLSt[p];
    const int cell = valid ? cellraw : 0;
    const int cols = COLSt[p];
    const int r = cell / cols;
    const int c = cell - r * cols;
    nkS[slot] = NKt[p];
    validS[slot] = valid;
    hbaseS[slot] = p * 6400 + r * 20 + c;
#pragma unroll
    for (int s = 0; s < 4; ++s) {
      kqS[slot][s] = KQt[p][s];
      cellxS[slot][s] = (r + DYt[p][s]) * 18 + (c + DXt[p][s]);
    }
  }

  f32x16 acc[3][2];
#pragma unroll
  for (int slot = 0; slot < 3; ++slot)
#pragma unroll
    for (int mf = 0; mf < 2; ++mf)
#pragma unroll
      for (int e = 0; e < 16; ++e) acc[slot][mf][e] = 0.f;

  // A-stage constants (threads 0..255): unit = (ocA, icgA) (verbatim R7)
  const int ocA = tid >> 2;
  const int icgA = tid & 3;
  const float* wA = w + (size_t)(octile * 64 + ocA) * 2304 + icgA * 36;

  // x-stage constants: 960 units, u = ic*60 + row*6 + f4g (f4g lane-minor ->
  // coalesced aligned f4 row loads); each writes 4 guarded b16 to xs[cell][ic]
  int uic_[2], urow_[2], uf4g_[2], ugh_[2], ugw0_[2];
  bool uact_[2], urowok_[2], ual_[2];
#pragma unroll
  for (int t = 0; t < 2; ++t) {
    const int u = tid + t * 512;
    uact_[t] = u < 960;
    const int uu = uact_[t] ? u : 0;
    uic_[t] = uu / 60;
    const int rem = uu - uic_[t] * 60;
    urow_[t] = rem / 6;
    uf4g_[t] = rem - urow_[t] * 6;
    ugh_[t] = A0 - 1 + urow_[t];
    urowok_[t] = (ugh_[t] >= 0) & (ugh_[t] < 64);
    ugw0_[t] = B0 - 4 + 4 * uf4g_[t];
    ual_[t] = (ugw0_[t] >= 0) & (ugw0_[t] <= 60);
  }

  // ---------------- K-loop: 16 chunks of 16 ic ----------------
  for (int cc = 0; cc < 16; ++cc) {
    // x-stage (all threads, 2 units): coalesced f4 loads -> b16 scatter
#pragma unroll
    for (int t = 0; t < 2; ++t) {
      if (uact_[t]) {
        float v[4] = {0.f, 0.f, 0.f, 0.f};
        if (urowok_[t]) {
          const float* base =
              x + (((size_t)(n * 256 + cc * 16 + uic_[t])) * 64 + ugh_[t]) * 64;
          if (ual_[t]) {
            const f32x4v fv = *(const f32x4v*)(base + ugw0_[t]);
#pragma unroll
            for (int e = 0; e < 4; ++e) v[e] = fv[e];
          } else {
#pragma unroll
            for (int e = 0; e < 4; ++e) {
              const int gw = ugw0_[t] + e;
              v[e] = (gw >= 0 && gw < 64) ? base[gw] : 0.f;
            }
          }
        }
#pragma unroll
        for (int e = 0; e < 4; ++e) {
          const int ww = 4 * uf4g_[t] + e - 3;
          if (ww >= 0 && ww < 18)
            xs[(urow_[t] * 18 + ww) * 16 + uic_[t]] = f2bf(v[e]);
        }
      }
    }
    // A-stage (threads 0..255, verbatim R7): 36 f4 w-loads, 9x2 b64 writes
    if (tid < 256) {
      float f36[36];
      const float* wp = wA + cc * 144;
#pragma unroll
      for (int f4 = 0; f4 < 9; ++f4)
        *(f32x4v*)&f36[f4 * 4] = *(const f32x4v*)(wp + f4 * 4);
#pragma unroll
      for (int kq = 0; kq < 9; ++kq) {
        bf16x4 pk;
#pragma unroll
        for (int v = 0; v < 4; ++v) pk[v] = f2bf(f36[v * 9 + kq]);
        *(bf16x4*)(As + kq * 1024 + ocA * 16 + icgA * 4) = pk;
      }
    }
    __syncthreads();

    // MFMA: per wave, its 3 slots; per slot, nk K-steps (verbatim R7)
#pragma unroll
    for (int slot = 0; slot < 3; ++slot) {
#pragma unroll
      for (int s = 0; s < 4; ++s) {
        if (s < nkS[slot]) {
          const int kq = kqS[slot][s];
          const bf16x8 B  = *(const bf16x8*)(xs + cellxS[slot][s] * 16 + q * 8);
          const bf16x8 Aa = *(const bf16x8*)(As + kq * 1024 + l31 * 16 + q * 8);
          const bf16x8 Ab = *(const bf16x8*)(As + kq * 1024 + (32 + l31) * 16 + q * 8);
          acc[slot][0] = __builtin_amdgcn_mfma_f32_32x32x16_bf16(Aa, B, acc[slot][0], 0, 0, 0);
          acc[slot][1] = __builtin_amdgcn_mfma_f32_32x32x16_bf16(Ab, B, acc[slot][1], 0, 0, 0);
        }
      }
    }
    __syncthreads();  // readers done before next restage
  }

  // ---------------- epilogue: 2 phases (mf = oc-half), verbatim R7 ----------------
  const float kf4[4] = {0.25f, 0.75f, 0.75f, 0.25f};
#pragma unroll
  for (int mf = 0; mf < 2; ++mf) {
    if (mf) __syncthreads();
#pragma unroll
    for (int slot = 0; slot < 3; ++slot) {
      if (validS[slot]) {
#pragma unroll
        for (int e = 0; e < 16; ++e) {
          const int ocl = (e & 3) + 8 * (e >> 2) + 4 * q;
          hl[hbaseS[slot] + ocl * 200] = f2bf(acc[slot][mf][e]);
        }
      }
    }
    __syncthreads();
    // FIR: 2048 units (ocl32 x Yl16 x g4), 4 per thread; coalesced out writes
#pragma unroll
    for (int k = 0; k < 4; ++k) {
      const int v = tid + k * 512;
      const int g = v & 3;
      const int Yl = (v >> 2) & 15;
      const int ocl = v >> 6;
      float o[8];
#pragma unroll
      for (int xx = 0; xx < 8; ++xx) o[xx] = 0.f;
#pragma unroll
      for (int du = 0; du < 4; ++du) {
        const int ttp = Yl - 1 + du;          // local fine h-row
        const int py = ttp & 1;
        const int r = py ? ((Yl + du) >> 1) : (ttp >> 1);
        const int baseE = (py * 2) * 6400 + ocl * 200 + r * 20 + 4 * g;
        const int baseO = (py * 2 + 1) * 6400 + ocl * 200 + r * 20 + 4 * g;
        const short4v e0 = *(const short4v*)(hl + baseE);
        const short4v e1 = *(const short4v*)(hl + baseE + 4);
        const short4v o0 = *(const short4v*)(hl + baseO);
        const short4v o1 = *(const short4v*)(hl + baseO + 4);
        float E[8], O[8];
#pragma unroll
        for (int i = 0; i < 4; ++i) {
          E[i] = bf2f(e0[i]); E[i + 4] = bf2f(e1[i]);
          O[i] = bf2f(o0[i]); O[i + 4] = bf2f(o1[i]);
        }
        float rx[8];
        rx[0] = 0.25f*O[0] + 0.75f*E[0] + 0.75f*O[1] + 0.25f*E[1];
        rx[1] = 0.25f*E[0] + 0.75f*O[1] + 0.75f*E[1] + 0.25f*O[2];
        rx[2] = 0.25f*O[1] + 0.75f*E[1] + 0.75f*O[2] + 0.25f*E[2];
        rx[3] = 0.25f*E[1] + 0.75f*O[2] + 0.75f*E[2] + 0.25f*O[3];
        rx[4] = 0.25f*O[2] + 0.75f*E[2] + 0.75f*O[3] + 0.25f*E[3];
        rx[5] = 0.25f*E[2] + 0.75f*O[3] + 0.75f*E[3] + 0.25f*O[4];
        rx[6] = 0.25f*O[3] + 0.75f*E[3] + 0.75f*O[4] + 0.25f*E[4];
        rx[7] = 0.25f*E[3] + 0.75f*O[4] + 0.75f*E[4] + 0.25f*O[5];
        const float ky = kf4[du];
#pragma unroll
        for (int xx = 0; xx < 8; ++xx) o[xx] += ky * rx[xx];
      }
      const int oc = octile * 64 + mf * 32 + ocl;
      const int Y = atile * 16 + Yl;
      const int X0 = btile * 32 + g * 8;
      float* op = out + (((size_t)(n * 256 + oc)) * 128 + Y) * 128 + X0;
      f32x4v v0, v1;
      v0[0] = o[0]; v0[1] = o[1]; v0[2] = o[2]; v0[3] = o[3];
      v1[0] = o[4]; v1[1] = o[5]; v1[2] = o[6]; v1[3] = o[7];
      *(f32x4v*)op = v0;
      *(f32x4v*)(op + 4) = v1;
    }
  }
}

extern "C" void kernel_launch(void* const* d_in, const int* in_sizes, int n_in,
                              void* d_out, int out_size, void* d_ws, size_t ws_size,
                              hipStream_t stream) {
  (void)in_sizes; (void)n_in; (void)out_size; (void)d_ws; (void)ws_size;
  const float* x = (const float*)d_in[0];
  const float* w = (const float*)d_in[1];
  float* out = (float*)d_out;
  // grid = 4 octiles x 4 n x 32 spatial = 512 blocks, 512 threads (8 waves)
  hipLaunchKernelGGL(fir_up_v13, dim3(512), dim3(512), 0, stream, x, w, out);
}

// Round 15
// 93.046 us; speedup vs baseline: 4.6585x; 1.1039x over previous
//
#include <hip/hip_runtime.h>

// FirUpsample R14 = R13 math + T3-minimum pipeline, unconfounded:
//   - ONE barrier per chunk (was 2): dbuf As/xs; per chunk issue x-loads for
//     cc+1 -> MFMA(cc) -> cvt+write cc+1 -> barrier. Global latency hides
//     under MFMA; no stage->barrier->compute->barrier serialization.
//   - LDS 54.1 KB (hl aliases both dbufs) -> 3 blocks/CU by LDS (was 75.8K/1-2).
//   - A-stage unit = (oc, ic-pair), all 512 thr, f18 regs (was f36/half thr)
//     -> fits no-spill under __launch_bounds__(512,2) (<=128 VGPR cap).
//   - xs cell stride 48B: write-side f4g collisions 6-way -> ~3-way.
// Math (verified R5-R13, absmax 0.015625): h = dilated conv3x3 as 4 parity-
// plane GEMMs (10.3 G MAC); separable 4-tap FIR epilogue from LDS.

typedef short short2v __attribute__((ext_vector_type(2)));
typedef short bf16x8 __attribute__((ext_vector_type(8)));
typedef short short4v __attribute__((ext_vector_type(4)));
typedef float f32x2v __attribute__((ext_vector_type(2)));
typedef float f32x16 __attribute__((ext_vector_type(16)));
typedef float f32x4v __attribute__((ext_vector_type(4)));

static __device__ __forceinline__ short f2bf(float f) {
  union { float f; unsigned u; } v; v.f = f;
  unsigned r = (v.u + 0x7FFFu + ((v.u >> 16) & 1u)) >> 16;
  return (short)r;
}
static __device__ __forceinline__ float bf2f(short s) {
  union { unsigned u; float f; } v; v.u = ((unsigned)(unsigned short)s) << 16;
  return v.f;
}

#define AS_SZ 18432           // one As buffer: [9 kq][64 oc][16 ic] bf16
#define XS_BASE 36864         // 2*AS_SZ
#define XS_SZ 8640            // one xs buffer: [180 cells][48 B]
#define XS_STRIDE 48

__global__ __launch_bounds__(512, 2)
void fir_up_v14(const float* __restrict__ x, const float* __restrict__ w,
                float* __restrict__ out) {
  __shared__ __align__(16) char smem[54144];

  const int bid = blockIdx.x;
  const int wg = (bid & 7) * 64 + (bid >> 3);
  const int octile = wg >> 7;        // 0..3 (64 oc each)
  const int n = (wg >> 5) & 3;
  const int sp = wg & 31;
  const int atile = sp >> 2;         // 8 coarse-row tiles
  const int btile = sp & 3;          // 4 coarse-col tiles
  const int A0 = atile * 8, B0 = btile * 16;

  const int tid = threadIdx.x;
  const int wid = tid >> 6;
  const int lane = tid & 63;
  const int l31 = lane & 31, q = lane >> 5;

  // ---- plane geometry + per-wave partition (verbatim R13, verified) ----
  const int COLSt[4]  = {17, 18, 17, 18};
  const int CELLSt[4] = {153, 162, 170, 180};
  const int NKt[4]    = {4, 2, 2, 1};
  const int KQt[4][4] = {{0,2,6,8},{1,7,7,7},{3,5,5,5},{4,4,4,4}};
  const int DYt[4][4] = {{0,0,1,1},{0,1,1,1},{0,0,0,0},{0,0,0,0}};
  const int DXt[4][4] = {{0,1,0,1},{0,0,0,0},{0,1,1,1},{0,0,0,0}};
  const unsigned long long PLbits =
      (0x34ULL) | (0x34ULL << 6) | (0x34ULL << 12) | (0x38ULL << 18) |
      (0x38ULL << 24) | (0x38ULL << 30) | (0x15ULL << 36) | (0x2AULL << 42);
  const unsigned FG0 = 0u | 1u<<3 | 2u<<6 | 3u<<9 | 4u<<12 | 5u<<15 | 3u<<18 | 3u<<21;
  const unsigned FG1 = 0u | 1u<<3 | 2u<<6 | 0u<<9 | 1u<<12 | 2u<<15 | 4u<<18 | 4u<<21;
  const unsigned FG2 = 0u | 1u<<3 | 2u<<6 | 3u<<9 | 4u<<12 | 5u<<15 | 5u<<18 | 5u<<21;

  int nkS[3], validS[3], hbaseS[3];
  int kqS[3][4], cellxS[3][4];
#pragma unroll
  for (int slot = 0; slot < 3; ++slot) {
    const int p = (int)((PLbits >> ((wid * 3 + slot) * 2)) & 3ULL);
    const unsigned fgw = slot == 0 ? FG0 : (slot == 1 ? FG1 : FG2);
    const int fg = (int)((fgw >> (3 * wid)) & 7u);
    const int cellraw = fg * 32 + l31;
    const int valid = cellraw < CELLSt[p];
    const int cell = valid ? cellraw : 0;
    const int cols = COLSt[p];
    const int r = cell / cols;
    const int c = cell - r * cols;
    nkS[slot] = NKt[p];
    validS[slot] = valid;
    hbaseS[slot] = p * 6400 + r * 20 + c;
#pragma unroll
    for (int s = 0; s < 4; ++s) {
      kqS[slot][s] = KQt[p][s];
      cellxS[slot][s] = (r + DYt[p][s]) * 18 + (c + DXt[p][s]);
    }
  }

  f32x16 acc[3][2];
#pragma unroll
  for (int slot = 0; slot < 3; ++slot)
#pragma unroll
    for (int mf = 0; mf < 2; ++mf)
#pragma unroll
      for (int e = 0; e < 16; ++e) acc[slot][mf][e] = 0.f;

  // ---- staging unit decode ----
  // A: unit = (ocA 0..63, icp 0..7): 18 consecutive floats = 2 ics x 9 kq
  const int ocA = tid >> 3, icp = tid & 7;
  const float* wA = w + (size_t)(octile * 64 + ocA) * 2304 + icp * 18;
  // x: 960 units, u = ic*60 + row*6 + f4g (f4g lane-minor, coalesced f4 rows)
  int uic_[2], urow_[2], uf4g_[2], ugh_[2], ugw0_[2];
  bool uact_[2], urowok_[2], ual_[2];
#pragma unroll
  for (int t = 0; t < 2; ++t) {
    const int u = tid + t * 512;
    uact_[t] = u < 960;
    const int uu = uact_[t] ? u : 0;
    uic_[t] = uu / 60;
    const int rem = uu - uic_[t] * 60;
    urow_[t] = rem / 6;
    uf4g_[t] = rem - urow_[t] * 6;
    ugh_[t] = A0 - 1 + urow_[t];
    urowok_[t] = (ugh_[t] >= 0) & (ugh_[t] < 64);
    ugw0_[t] = B0 - 4 + 4 * uf4g_[t];
    ual_[t] = (ugw0_[t] >= 0) & (ugw0_[t] <= 60);
  }

  // ---- prologue: stage chunk 0 into buffers 0 ----
  {
    char* xsw = smem + XS_BASE;
#pragma unroll
    for (int t = 0; t < 2; ++t) {
      if (uact_[t]) {
        float v[4] = {0.f, 0.f, 0.f, 0.f};
        if (urowok_[t]) {
          const float* base = x + (((size_t)(n * 256 + uic_[t])) * 64 + ugh_[t]) * 64;
          if (ual_[t]) {
            const f32x4v fv = *(const f32x4v*)(base + ugw0_[t]);
#pragma unroll
            for (int e = 0; e < 4; ++e) v[e] = fv[e];
          } else {
#pragma unroll
            for (int e = 0; e < 4; ++e) {
              const int gw = ugw0_[t] + e;
              v[e] = (gw >= 0 && gw < 64) ? base[gw] : 0.f;
            }
          }
        }
#pragma unroll
        for (int e = 0; e < 4; ++e) {
          const int ww = 4 * uf4g_[t] + e - 3;
          if (ww >= 0 && ww < 18)
            *(short*)(xsw + (urow_[t] * 18 + ww) * XS_STRIDE + uic_[t] * 2) = f2bf(v[e]);
        }
      }
    }
    float f18[18];
#pragma unroll
    for (int j = 0; j < 9; ++j)
      *(f32x2v*)&f18[2 * j] = *(const f32x2v*)(wA + 2 * j);
#pragma unroll
    for (int kq = 0; kq < 9; ++kq) {
      short2v pk;
      pk[0] = f2bf(f18[kq]);
      pk[1] = f2bf(f18[kq + 9]);
      *(short2v*)(smem + kq * 2048 + ocA * 32 + icp * 4) = pk;
    }
  }
  __syncthreads();

  // ---------------- K-loop: 16 chunks, ONE barrier each ----------------
  for (int cc = 0; cc < 16; ++cc) {
    char* Asr = smem + (cc & 1) * AS_SZ;
    char* xsr = smem + XS_BASE + (cc & 1) * XS_SZ;
    char* Asw = smem + ((cc + 1) & 1) * AS_SZ;
    char* xsw = smem + XS_BASE + ((cc + 1) & 1) * XS_SZ;
    const bool have = cc < 15;

    // issue x loads for chunk cc+1 (latency hides under MFMA below)
    float xv[2][4];
#pragma unroll
    for (int t = 0; t < 2; ++t) {
#pragma unroll
      for (int e = 0; e < 4; ++e) xv[t][e] = 0.f;
      if (have && uact_[t] && urowok_[t]) {
        const float* base =
            x + (((size_t)(n * 256 + (cc + 1) * 16 + uic_[t])) * 64 + ugh_[t]) * 64;
        if (ual_[t]) {
          const f32x4v fv = *(const f32x4v*)(base + ugw0_[t]);
#pragma unroll
          for (int e = 0; e < 4; ++e) xv[t][e] = fv[e];
        } else {
#pragma unroll
          for (int e = 0; e < 4; ++e) {
            const int gw = ugw0_[t] + e;
            xv[t][e] = (gw >= 0 && gw < 64) ? base[gw] : 0.f;
          }
        }
      }
    }

    // MFMA on chunk cc (reads buf cur; verbatim R13 partition)
#pragma unroll
    for (int slot = 0; slot < 3; ++slot) {
#pragma unroll
      for (int s = 0; s < 4; ++s) {
        if (s < nkS[slot]) {
          const int kq = kqS[slot][s];
          const bf16x8 B  = *(const bf16x8*)(xsr + cellxS[slot][s] * XS_STRIDE + q * 16);
          const bf16x8 Aa = *(const bf16x8*)(Asr + kq * 2048 + l31 * 32 + q * 16);
          const bf16x8 Ab = *(const bf16x8*)(Asr + kq * 2048 + 1024 + l31 * 32 + q * 16);
          acc[slot][0] = __builtin_amdgcn_mfma_f32_32x32x16_bf16(Aa, B, acc[slot][0], 0, 0, 0);
          acc[slot][1] = __builtin_amdgcn_mfma_f32_32x32x16_bf16(Ab, B, acc[slot][1], 0, 0, 0);
        }
      }
    }

    if (have) {
      // write staged x (xv dead after -> frees regs before A-stage)
#pragma unroll
      for (int t = 0; t < 2; ++t) {
        if (uact_[t]) {
#pragma unroll
          for (int e = 0; e < 4; ++e) {
            const int ww = 4 * uf4g_[t] + e - 3;
            if (ww >= 0 && ww < 18)
              *(short*)(xsw + (urow_[t] * 18 + ww) * XS_STRIDE + uic_[t] * 2) = f2bf(xv[t][e]);
          }
        }
      }
      // A-stage chunk cc+1: 9 f2 loads (L2-resident w), 9 b32 writes
      float f18[18];
      const float* wp = wA + (cc + 1) * 144;
#pragma unroll
      for (int j = 0; j < 9; ++j)
        *(f32x2v*)&f18[2 * j] = *(const f32x2v*)(wp + 2 * j);
#pragma unroll
      for (int kq = 0; kq < 9; ++kq) {
        short2v pk;
        pk[0] = f2bf(f18[kq]);
        pk[1] = f2bf(f18[kq + 9]);
        *(short2v*)(Asw + kq * 2048 + ocA * 32 + icp * 4) = pk;
      }
    }
    __syncthreads();
  }

  // ---------------- epilogue: 2 phases (mf = oc-half), verbatim R13 ----------------
  short* hl = (short*)smem;
  const float kf4[4] = {0.25f, 0.75f, 0.75f, 0.25f};
#pragma unroll
  for (int mf = 0; mf < 2; ++mf) {
    if (mf) __syncthreads();
#pragma unroll
    for (int slot = 0; slot < 3; ++slot) {
      if (validS[slot]) {
#pragma unroll
        for (int e = 0; e < 16; ++e) {
          const int ocl = (e & 3) + 8 * (e >> 2) + 4 * q;
          hl[hbaseS[slot] + ocl * 200] = f2bf(acc[slot][mf][e]);
        }
      }
    }
    __syncthreads();
#pragma unroll
    for (int k = 0; k < 4; ++k) {
      const int v = tid + k * 512;
      const int g = v & 3;
      const int Yl = (v >> 2) & 15;
      const int ocl = v >> 6;
      float o[8];
#pragma unroll
      for (int xx = 0; xx < 8; ++xx) o[xx] = 0.f;
#pragma unroll
      for (int du = 0; du < 4; ++du) {
        const int ttp = Yl - 1 + du;
        const int py = ttp & 1;
        const int r = py ? ((Yl + du) >> 1) : (ttp >> 1);
        const int baseE = (py * 2) * 6400 + ocl * 200 + r * 20 + 4 * g;
        const int baseO = (py * 2 + 1) * 6400 + ocl * 200 + r * 20 + 4 * g;
        const short4v e0 = *(const short4v*)(hl + baseE);
        const short4v e1 = *(const short4v*)(hl + baseE + 4);
        const short4v o0 = *(const short4v*)(hl + baseO);
        const short4v o1 = *(const short4v*)(hl + baseO + 4);
        float E[8], O[8];
#pragma unroll
        for (int i = 0; i < 4; ++i) {
          E[i] = bf2f(e0[i]); E[i + 4] = bf2f(e1[i]);
          O[i] = bf2f(o0[i]); O[i + 4] = bf2f(o1[i]);
        }
        float rx[8];
        rx[0] = 0.25f*O[0] + 0.75f*E[0] + 0.75f*O[1] + 0.25f*E[1];
        rx[1] = 0.25f*E[0] + 0.75f*O[1] + 0.75f*E[1] + 0.25f*O[2];
        rx[2] = 0.25f*O[1] + 0.75f*E[1] + 0.75f*O[2] + 0.25f*E[2];
        rx[3] = 0.25f*E[1] + 0.75f*O[2] + 0.75f*E[2] + 0.25f*O[3];
        rx[4] = 0.25f*O[2] + 0.75f*E[2] + 0.75f*O[3] + 0.25f*E[3];
        rx[5] = 0.25f*E[2] + 0.75f*O[3] + 0.75f*E[3] + 0.25f*O[4];
        rx[6] = 0.25f*O[3] + 0.75f*E[3] + 0.75f*O[4] + 0.25f*E[4];
        rx[7] = 0.25f*E[3] + 0.75f*O[4] + 0.75f*E[4] + 0.25f*O[5];
        const float ky = kf4[du];
#pragma unroll
        for (int xx = 0; xx < 8; ++xx) o[xx] += ky * rx[xx];
      }
      const int oc = octile * 64 + mf * 32 + ocl;
      const int Y = atile * 16 + Yl;
      const int X0 = btile * 32 + g * 8;
      float* op = out + (((size_t)(n * 256 + oc)) * 128 + Y) * 128 + X0;
      f32x4v v0, v1;
      v0[0] = o[0]; v0[1] = o[1]; v0[2] = o[2]; v0[3] = o[3];
      v1[0] = o[4]; v1[1] = o[5]; v1[2] = o[6]; v1[3] = o[7];
      *(f32x4v*)op = v0;
      *(f32x4v*)(op + 4) = v1;
    }
  }
}

extern "C" void kernel_launch(void* const* d_in, const int* in_sizes, int n_in,
                              void* d_out, int out_size, void* d_ws, size_t ws_size,
                              hipStream_t stream) {
  (void)in_sizes; (void)n_in; (void)out_size; (void)d_ws; (void)ws_size;
  const float* x = (const float*)d_in[0];
  const float* w = (const float*)d_in[1];
  float* out = (float*)d_out;
  // grid = 4 octiles x 4 n x 32 spatial = 512 blocks, 512 threads
  hipLaunchKernelGGL(fir_up_v14, dim3(512), dim3(512), 0, stream, x, w, out);
}

// Round 16
// 91.939 us; speedup vs baseline: 4.7146x; 1.0120x over previous
//
#include <hip/hip_runtime.h>
#include <hip/hip_bf16.h>

// FirUpsample R15 = R14 (93us, single-barrier dbuf pipeline) + VALU reduction:
//   (a) native __float2bfloat16 instead of hand-rolled bit-twiddle f2bf
//       (compiler emits packed v_cvt_pk_bf16_f32; manual version was ~4 VALU
//       ops/value and was the largest busy term: VALU 30us vs MFMA 11us),
//   (b) unguarded interior path for the x-stage LDS scatter (f4g 1..4 always
//       in-bounds: ww = 4*f4g-3+e in [1,16]),
//   (c) s_setprio(1) around the MFMA cluster (waves have role diversity).
// Math (verified R5-R14, absmax 0.015625): h = dilated conv3x3 as 4 parity-
// plane GEMMs (10.3 G MAC); separable 4-tap FIR epilogue from LDS.

typedef short short2v __attribute__((ext_vector_type(2)));
typedef short bf16x8 __attribute__((ext_vector_type(8)));
typedef short short4v __attribute__((ext_vector_type(4)));
typedef float f32x2v __attribute__((ext_vector_type(2)));
typedef float f32x16 __attribute__((ext_vector_type(16)));
typedef float f32x4v __attribute__((ext_vector_type(4)));

static __device__ __forceinline__ short f2bf(float f) {
  __hip_bfloat16 h = __float2bfloat16(f);   // native cvt, RNE
  union { __hip_bfloat16 h; short s; } u; u.h = h;
  return u.s;
}
static __device__ __forceinline__ float bf2f(short s) {
  union { unsigned u; float f; } v; v.u = ((unsigned)(unsigned short)s) << 16;
  return v.f;
}

#define AS_SZ 18432           // one As buffer: [9 kq][64 oc][16 ic] bf16
#define XS_BASE 36864         // 2*AS_SZ
#define XS_SZ 8640            // one xs buffer: [180 cells][48 B]
#define XS_STRIDE 48

__global__ __launch_bounds__(512, 2)
void fir_up_v15(const float* __restrict__ x, const float* __restrict__ w,
                float* __restrict__ out) {
  __shared__ __align__(16) char smem[54144];

  const int bid = blockIdx.x;
  const int wg = (bid & 7) * 64 + (bid >> 3);
  const int octile = wg >> 7;        // 0..3 (64 oc each)
  const int n = (wg >> 5) & 3;
  const int sp = wg & 31;
  const int atile = sp >> 2;         // 8 coarse-row tiles
  const int btile = sp & 3;          // 4 coarse-col tiles
  const int A0 = atile * 8, B0 = btile * 16;

  const int tid = threadIdx.x;
  const int wid = tid >> 6;
  const int lane = tid & 63;
  const int l31 = lane & 31, q = lane >> 5;

  // ---- plane geometry + per-wave partition (verbatim R13/R14, verified) ----
  const int COLSt[4]  = {17, 18, 17, 18};
  const int CELLSt[4] = {153, 162, 170, 180};
  const int NKt[4]    = {4, 2, 2, 1};
  const int KQt[4][4] = {{0,2,6,8},{1,7,7,7},{3,5,5,5},{4,4,4,4}};
  const int DYt[4][4] = {{0,0,1,1},{0,1,1,1},{0,0,0,0},{0,0,0,0}};
  const int DXt[4][4] = {{0,1,0,1},{0,0,0,0},{0,1,1,1},{0,0,0,0}};
  const unsigned long long PLbits =
      (0x34ULL) | (0x34ULL << 6) | (0x34ULL << 12) | (0x38ULL << 18) |
      (0x38ULL << 24) | (0x38ULL << 30) | (0x15ULL << 36) | (0x2AULL << 42);
  const unsigned FG0 = 0u | 1u<<3 | 2u<<6 | 3u<<9 | 4u<<12 | 5u<<15 | 3u<<18 | 3u<<21;
  const unsigned FG1 = 0u | 1u<<3 | 2u<<6 | 0u<<9 | 1u<<12 | 2u<<15 | 4u<<18 | 4u<<21;
  const unsigned FG2 = 0u | 1u<<3 | 2u<<6 | 3u<<9 | 4u<<12 | 5u<<15 | 5u<<18 | 5u<<21;

  int nkS[3], validS[3], hbaseS[3];
  int kqS[3][4], cellxS[3][4];
#pragma unroll
  for (int slot = 0; slot < 3; ++slot) {
    const int p = (int)((PLbits >> ((wid * 3 + slot) * 2)) & 3ULL);
    const unsigned fgw = slot == 0 ? FG0 : (slot == 1 ? FG1 : FG2);
    const int fg = (int)((fgw >> (3 * wid)) & 7u);
    const int cellraw = fg * 32 + l31;
    const int valid = cellraw < CELLSt[p];
    const int cell = valid ? cellraw : 0;
    const int cols = COLSt[p];
    const int r = cell / cols;
    const int c = cell - r * cols;
    nkS[slot] = NKt[p];
    validS[slot] = valid;
    hbaseS[slot] = p * 6400 + r * 20 + c;
#pragma unroll
    for (int s = 0; s < 4; ++s) {
      kqS[slot][s] = KQt[p][s];
      cellxS[slot][s] = (r + DYt[p][s]) * 18 + (c + DXt[p][s]);
    }
  }

  f32x16 acc[3][2];
#pragma unroll
  for (int slot = 0; slot < 3; ++slot)
#pragma unroll
    for (int mf = 0; mf < 2; ++mf)
#pragma unroll
      for (int e = 0; e < 16; ++e) acc[slot][mf][e] = 0.f;

  // ---- staging unit decode ----
  const int ocA = tid >> 3, icp = tid & 7;
  const float* wA = w + (size_t)(octile * 64 + ocA) * 2304 + icp * 18;
  int uic_[2], urow_[2], uf4g_[2], ugh_[2], ugw0_[2], uwb0_[2];
  bool uact_[2], urowok_[2], ual_[2], uint_[2];
#pragma unroll
  for (int t = 0; t < 2; ++t) {
    const int u = tid + t * 512;
    uact_[t] = u < 960;
    const int uu = uact_[t] ? u : 0;
    uic_[t] = uu / 60;
    const int rem = uu - uic_[t] * 60;
    urow_[t] = rem / 6;
    uf4g_[t] = rem - urow_[t] * 6;
    ugh_[t] = A0 - 1 + urow_[t];
    urowok_[t] = (ugh_[t] >= 0) & (ugh_[t] < 64);
    ugw0_[t] = B0 - 4 + 4 * uf4g_[t];
    ual_[t] = (ugw0_[t] >= 0) & (ugw0_[t] <= 60);
    uint_[t] = (uf4g_[t] >= 1) & (uf4g_[t] <= 4);   // interior: ww 1..16 valid
    uwb0_[t] = (urow_[t] * 18 + (4 * uf4g_[t] - 3)) * XS_STRIDE + uic_[t] * 2;
  }

  // ---- prologue: stage chunk 0 into buffers 0 ----
  {
    char* xsw = smem + XS_BASE;
#pragma unroll
    for (int t = 0; t < 2; ++t) {
      if (uact_[t]) {
        float v[4] = {0.f, 0.f, 0.f, 0.f};
        if (urowok_[t]) {
          const float* base = x + (((size_t)(n * 256 + uic_[t])) * 64 + ugh_[t]) * 64;
          if (ual_[t]) {
            const f32x4v fv = *(const f32x4v*)(base + ugw0_[t]);
#pragma unroll
            for (int e = 0; e < 4; ++e) v[e] = fv[e];
          } else {
#pragma unroll
            for (int e = 0; e < 4; ++e) {
              const int gw = ugw0_[t] + e;
              v[e] = (gw >= 0 && gw < 64) ? base[gw] : 0.f;
            }
          }
        }
        if (uint_[t]) {
#pragma unroll
          for (int e = 0; e < 4; ++e)
            *(short*)(xsw + uwb0_[t] + e * XS_STRIDE) = f2bf(v[e]);
        } else {
#pragma unroll
          for (int e = 0; e < 4; ++e) {
            const int ww = 4 * uf4g_[t] + e - 3;
            if (ww >= 0 && ww < 18)
              *(short*)(xsw + (urow_[t] * 18 + ww) * XS_STRIDE + uic_[t] * 2) = f2bf(v[e]);
          }
        }
      }
    }
    float f18[18];
#pragma unroll
    for (int j = 0; j < 9; ++j)
      *(f32x2v*)&f18[2 * j] = *(const f32x2v*)(wA + 2 * j);
#pragma unroll
    for (int kq = 0; kq < 9; ++kq) {
      short2v pk;
      pk[0] = f2bf(f18[kq]);
      pk[1] = f2bf(f18[kq + 9]);
      *(short2v*)(smem + kq * 2048 + ocA * 32 + icp * 4) = pk;
    }
  }
  __syncthreads();

  // ---------------- K-loop: 16 chunks, ONE barrier each ----------------
  for (int cc = 0; cc < 16; ++cc) {
    char* Asr = smem + (cc & 1) * AS_SZ;
    char* xsr = smem + XS_BASE + (cc & 1) * XS_SZ;
    char* Asw = smem + ((cc + 1) & 1) * AS_SZ;
    char* xsw = smem + XS_BASE + ((cc + 1) & 1) * XS_SZ;
    const bool have = cc < 15;

    // issue x loads for chunk cc+1 (latency hides under MFMA below)
    float xv[2][4];
#pragma unroll
    for (int t = 0; t < 2; ++t) {
#pragma unroll
      for (int e = 0; e < 4; ++e) xv[t][e] = 0.f;
      if (have && uact_[t] && urowok_[t]) {
        const float* base =
            x + (((size_t)(n * 256 + (cc + 1) * 16 + uic_[t])) * 64 + ugh_[t]) * 64;
        if (ual_[t]) {
          const f32x4v fv = *(const f32x4v*)(base + ugw0_[t]);
#pragma unroll
          for (int e = 0; e < 4; ++e) xv[t][e] = fv[e];
        } else {
#pragma unroll
          for (int e = 0; e < 4; ++e) {
            const int gw = ugw0_[t] + e;
            xv[t][e] = (gw >= 0 && gw < 64) ? base[gw] : 0.f;
          }
        }
      }
    }

    // MFMA on chunk cc (verbatim R14 partition), prioritized
    __builtin_amdgcn_s_setprio(1);
#pragma unroll
    for (int slot = 0; slot < 3; ++slot) {
#pragma unroll
      for (int s = 0; s < 4; ++s) {
        if (s < nkS[slot]) {
          const int kq = kqS[slot][s];
          const bf16x8 B  = *(const bf16x8*)(xsr + cellxS[slot][s] * XS_STRIDE + q * 16);
          const bf16x8 Aa = *(const bf16x8*)(Asr + kq * 2048 + l31 * 32 + q * 16);
          const bf16x8 Ab = *(const bf16x8*)(Asr + kq * 2048 + 1024 + l31 * 32 + q * 16);
          acc[slot][0] = __builtin_amdgcn_mfma_f32_32x32x16_bf16(Aa, B, acc[slot][0], 0, 0, 0);
          acc[slot][1] = __builtin_amdgcn_mfma_f32_32x32x16_bf16(Ab, B, acc[slot][1], 0, 0, 0);
        }
      }
    }
    __builtin_amdgcn_s_setprio(0);

    if (have) {
#pragma unroll
      for (int t = 0; t < 2; ++t) {
        if (uact_[t]) {
          if (uint_[t]) {
#pragma unroll
            for (int e = 0; e < 4; ++e)
              *(short*)(xsw + uwb0_[t] + e * XS_STRIDE) = f2bf(xv[t][e]);
          } else {
#pragma unroll
            for (int e = 0; e < 4; ++e) {
              const int ww = 4 * uf4g_[t] + e - 3;
              if (ww >= 0 && ww < 18)
                *(short*)(xsw + (urow_[t] * 18 + ww) * XS_STRIDE + uic_[t] * 2) = f2bf(xv[t][e]);
            }
          }
        }
      }
      float f18[18];
      const float* wp = wA + (cc + 1) * 144;
#pragma unroll
      for (int j = 0; j < 9; ++j)
        *(f32x2v*)&f18[2 * j] = *(const f32x2v*)(wp + 2 * j);
#pragma unroll
      for (int kq = 0; kq < 9; ++kq) {
        short2v pk;
        pk[0] = f2bf(f18[kq]);
        pk[1] = f2bf(f18[kq + 9]);
        *(short2v*)(Asw + kq * 2048 + ocA * 32 + icp * 4) = pk;
      }
    }
    __syncthreads();
  }

  // ---------------- epilogue: 2 phases (mf = oc-half), verbatim R14 ----------------
  short* hl = (short*)smem;
  const float kf4[4] = {0.25f, 0.75f, 0.75f, 0.25f};
#pragma unroll
  for (int mf = 0; mf < 2; ++mf) {
    if (mf) __syncthreads();
#pragma unroll
    for (int slot = 0; slot < 3; ++slot) {
      if (validS[slot]) {
#pragma unroll
        for (int e = 0; e < 16; ++e) {
          const int ocl = (e & 3) + 8 * (e >> 2) + 4 * q;
          hl[hbaseS[slot] + ocl * 200] = f2bf(acc[slot][mf][e]);
        }
      }
    }
    __syncthreads();
#pragma unroll
    for (int k = 0; k < 4; ++k) {
      const int v = tid + k * 512;
      const int g = v & 3;
      const int Yl = (v >> 2) & 15;
      const int ocl = v >> 6;
      float o[8];
#pragma unroll
      for (int xx = 0; xx < 8; ++xx) o[xx] = 0.f;
#pragma unroll
      for (int du = 0; du < 4; ++du) {
        const int ttp = Yl - 1 + du;
        const int py = ttp & 1;
        const int r = py ? ((Yl + du) >> 1) : (ttp >> 1);
        const int baseE = (py * 2) * 6400 + ocl * 200 + r * 20 + 4 * g;
        const int baseO = (py * 2 + 1) * 6400 + ocl * 200 + r * 20 + 4 * g;
        const short4v e0 = *(const short4v*)(hl + baseE);
        const short4v e1 = *(const short4v*)(hl + baseE + 4);
        const short4v o0 = *(const short4v*)(hl + baseO);
        const short4v o1 = *(const short4v*)(hl + baseO + 4);
        float E[8], O[8];
#pragma unroll
        for (int i = 0; i < 4; ++i) {
          E[i] = bf2f(e0[i]); E[i + 4] = bf2f(e1[i]);
          O[i] = bf2f(o0[i]); O[i + 4] = bf2f(o1[i]);
        }
        float rx[8];
        rx[0] = 0.25f*O[0] + 0.75f*E[0] + 0.75f*O[1] + 0.25f*E[1];
        rx[1] = 0.25f*E[0] + 0.75f*O[1] + 0.75f*E[1] + 0.25f*O[2];
        rx[2] = 0.25f*O[1] + 0.75f*E[1] + 0.75f*O[2] + 0.25f*E[2];
        rx[3] = 0.25f*E[1] + 0.75f*O[2] + 0.75f*E[2] + 0.25f*O[3];
        rx[4] = 0.25f*O[2] + 0.75f*E[2] + 0.75f*O[3] + 0.25f*E[3];
        rx[5] = 0.25f*E[2] + 0.75f*O[3] + 0.75f*E[3] + 0.25f*O[4];
        rx[6] = 0.25f*O[3] + 0.75f*E[3] + 0.75f*O[4] + 0.25f*E[4];
        rx[7] = 0.25f*E[3] + 0.75f*O[4] + 0.75f*E[4] + 0.25f*O[5];
        const float ky = kf4[du];
#pragma unroll
        for (int xx = 0; xx < 8; ++xx) o[xx] += ky * rx[xx];
      }
      const int oc = octile * 64 + mf * 32 + ocl;
      const int Y = atile * 16 + Yl;
      const int X0 = btile * 32 + g * 8;
      float* op = out + (((size_t)(n * 256 + oc)) * 128 + Y) * 128 + X0;
      f32x4v v0, v1;
      v0[0] = o[0]; v0[1] = o[1]; v0[2] = o[2]; v0[3] = o[3];
      v1[0] = o[4]; v1[1] = o[5]; v1[2] = o[6]; v1[3] = o[7];
      *(f32x4v*)op = v0;
      *(f32x4v*)(op + 4) = v1;
    }
  }
}

extern "C" void kernel_launch(void* const* d_in, const int* in_sizes, int n_in,
                              void* d_out, int out_size, void* d_ws, size_t ws_size,
                              hipStream_t stream) {
  (void)in_sizes; (void)n_in; (void)out_size; (void)d_ws; (void)ws_size;
  const float* x = (const float*)d_in[0];
  const float* w = (const float*)d_in[1];
  float* out = (float*)d_out;
  // grid = 4 octiles x 4 n x 32 spatial = 512 blocks, 512 threads
  hipLaunchKernelGGL(fir_up_v15, dim3(512), dim3(512), 0, stream, x, w, out);
}